// Round 5
// baseline (105.751 us; speedup 1.0000x reference)
//
#include <hip/hip_runtime.h>
#include <math.h>

constexpr int N_RAYS = 65536;
constexpr int NBLK   = 2048;     // 2048 blocks * 4 waves = 8192 waves
constexpr int WAVES  = NBLK * 4;

// DPP helper: lanes with a valid source get dpp(src); invalid lanes keep `oldv`.
// (row = 16 lanes; row_shr:n = lane i reads lane i-n; row_shl:n = lane i+n)
template<int CTRL>
__device__ __forceinline__ float dppf(float oldv, float x) {
    return __int_as_float(__builtin_amdgcn_update_dpp(
        __float_as_int(oldv), __float_as_int(x), CTRL, 0xF, 0xF, false));
}

__device__ __forceinline__ float row16_sum(float x) {
    x += dppf<0xB1>(0.0f, x);    // quad_perm(1,0,3,2)
    x += dppf<0x4E>(0.0f, x);    // quad_perm(2,3,0,1)
    x += dppf<0x141>(0.0f, x);   // row_half_mirror
    x += dppf<0x140>(0.0f, x);   // row_mirror
    return x;
}
__device__ __forceinline__ float row16_prod(float x) {
    x *= dppf<0xB1>(1.0f, x);
    x *= dppf<0x4E>(1.0f, x);
    x *= dppf<0x141>(1.0f, x);
    x *= dppf<0x140>(1.0f, x);
    return x;
}

// One wave = 4 rays (16 lanes/ray), strided sample ownership (lane m owns
// samples {16j+m}). All cross-lane ops DPP. Fused finale: per-block entropy
// partial -> d_ws, ticket atomicAdd, last block reduces partials in fixed
// lane order (bit-deterministic) and writes the sparsity scalar.
__global__ __launch_bounds__(256) void integrate_kernel(
    const float* __restrict__ raw,     // [N][128][4]
    const float* __restrict__ zvals,   // [N][128]
    const float* __restrict__ rays_d,  // [N][3]
    float* __restrict__ chs_map,       // [N][3]
    float* __restrict__ depth_map,     // [N]
    float* __restrict__ block_partials,
    int* __restrict__ counter,
    float* __restrict__ sparsity_out)
{
    const int lane = threadIdx.x & 63;
    const int warp = threadIdx.x >> 6;
    const int g    = lane >> 4;   // ray within wave
    const int m    = lane & 15;   // lane within ray group

    float ent_acc = 0.0f;
    const int gw = blockIdx.x * 4 + warp;

    #pragma unroll
    for (int k = 0; k < 2; ++k) {
        const int ray = (gw + k * WAVES) * 4 + g;

        const float* rd = rays_d + (size_t)ray * 3;
        const float norm = sqrtf(rd[0]*rd[0] + rd[1]*rd[1] + rd[2]*rd[2]);

        // z: 8 coalesced scalar loads (chunk jj, lane m -> z[16*jj + m])
        const float* zr = zvals + (size_t)ray * 128;
        float z[8];
        #pragma unroll
        for (int jj = 0; jj < 8; ++jj) z[jj] = zr[16*jj + m];

        const float4* rq = (const float4*)raw + (size_t)ray * 128;

        float c0=0.f, c1=0.f, c2=0.f, wsum=0.f, dnum=0.f, aa=0.f;
        float carry = 1.0f;

        #pragma unroll
        for (int h = 0; h < 2; ++h) {
            float4 q[4];
            #pragma unroll
            for (int j = 0; j < 4; ++j) q[j] = rq[h*64 + 16*j + m];

            #pragma unroll
            for (int j = 0; j < 4; ++j) {
                const int jj = h*4 + j;
                const float zc = z[jj];
                // z[s+1]: lanes 0..14 via row_shl:1; lane 15 gets next chunk's
                // lane-0 value via row_shr:15 (jj==7 lane15 overridden below)
                const float znfix = dppf<0x11F>(zc, z[(jj < 7) ? jj+1 : jj]);
                const float zn    = dppf<0x101>(znfix, zc);
                const bool  last  = (jj == 7) && (m == 15);   // s == 127
                const float dn    = last ? (1e10f * norm) : ((zn - zc) * norm);

                const float sig   = fmaxf(q[j].w, 0.0f);
                const float e     = __expf(-sig * dn);
                const float alpha = 1.0f - e;
                const float t     = e + 1e-10f;

                // inclusive product scan over the 16-lane chunk
                float sc = t;
                sc *= dppf<0x111>(1.0f, sc);   // row_shr:1
                sc *= dppf<0x112>(1.0f, sc);   // row_shr:2
                sc *= dppf<0x114>(1.0f, sc);   // row_shr:4
                sc *= dppf<0x118>(1.0f, sc);   // row_shr:8
                const float E = dppf<0x111>(1.0f, sc);   // exclusive (lane0=1)
                const float T = row16_prod(t);           // chunk total

                const float trans = carry * E;
                const float w     = alpha * trans;
                c0   += w * q[j].x;
                c1   += w * q[j].y;
                c2   += w * q[j].z;
                wsum += w;
                dnum += w * (6.0f - zc) * 0.25f;
                aa   += w * __logf(fmaxf(w, 1e-30f));   // w==0 -> 0*log(eps)=0
                carry *= T;
            }
        }

        // 6-var allreduce within the 16-lane group (pure DPP)
        c0   = row16_sum(c0);
        c1   = row16_sum(c1);
        c2   = row16_sum(c2);
        wsum = row16_sum(wsum);
        dnum = row16_sum(dnum);
        aa   = row16_sum(aa);

        if (m == 0) {
            chs_map[(size_t)ray * 3 + 0] = c0;
            chs_map[(size_t)ray * 3 + 1] = c1;
            chs_map[(size_t)ray * 3 + 2] = c2;
            depth_map[ray] = dnum / (wsum + 1e-5f);

            // sum p*log p = (A - W*log(psum) + L*(log L - log psum)) / psum
            const float L = 1.0f - wsum + 1e-6f;
            const float psum = wsum + L;
            const float logpsum = __logf(psum);
            const float entL = (L > 0.0f) ? L * (__logf(L) - logpsum) : 0.0f;
            ent_acc -= (aa - wsum * logpsum + entL) / psum;
        }
    }

    // entropy partials on lanes 0,16,32,48 -> lane 0
    ent_acc += __shfl_xor(ent_acc, 16);
    ent_acc += __shfl_xor(ent_acc, 32);

    __shared__ float sred[4];
    __shared__ int slast;
    if (lane == 0) sred[warp] = ent_acc;
    __syncthreads();
    if (threadIdx.x == 0) {
        block_partials[blockIdx.x] = sred[0] + sred[1] + sred[2] + sred[3];
        __threadfence();                       // publish partial device-wide
        const int t = atomicAdd(counter, 1);   // device-scope ticket
        slast = (t == NBLK - 1) ? 1 : 0;
    }
    __syncthreads();

    if (slast && threadIdx.x < 64) {
        // last-finishing block: all partials are published; reduce in fixed
        // lane-strided order -> bit-deterministic result
        float s2 = 0.0f;
        for (int i = threadIdx.x; i < NBLK; i += 64)
            s2 += __hip_atomic_load(&block_partials[i], __ATOMIC_RELAXED,
                                    __HIP_MEMORY_SCOPE_AGENT);
        #pragma unroll
        for (int d = 1; d < 64; d <<= 1) s2 += __shfl_xor(s2, d);
        if (threadIdx.x == 0) *sparsity_out = s2;
    }
}

extern "C" void kernel_launch(void* const* d_in, const int* in_sizes, int n_in,
                              void* d_out, int out_size, void* d_ws, size_t ws_size,
                              hipStream_t stream) {
    const float* raw    = (const float*)d_in[0];
    const float* zvals  = (const float*)d_in[1];
    const float* rays_d = (const float*)d_in[2];

    float* out = (float*)d_out;
    float* chs_map   = out;                       // 65536*3
    float* depth_map = out + (size_t)N_RAYS * 3;  // 65536
    float* sparsity  = out + (size_t)N_RAYS * 4;  // 1

    float* partials = (float*)d_ws;                         // NBLK floats
    int*   counter  = (int*)((char*)d_ws + NBLK * sizeof(float));

    // zero the ticket counter each call (graph-capturable async memset;
    // d_ws is NOT re-poisoned between replays, so this must be per-launch)
    hipMemsetAsync(counter, 0, sizeof(int), stream);

    integrate_kernel<<<NBLK, 256, 0, stream>>>(raw, zvals, rays_d,
                                               chs_map, depth_map,
                                               partials, counter, sparsity);
}

// Round 6
// 68.716 us; speedup vs baseline: 1.5390x; 1.5390x over previous
//
#include <hip/hip_runtime.h>
#include <math.h>

constexpr int N_RAYS = 65536;
constexpr int NBLK   = 4096;   // 4096 blocks * 4 waves * 4 rays = 65536 rays

// DPP helper: lanes with a valid source get dpp(src); invalid lanes keep `oldv`.
// (row = 16 lanes; row_shr:n = lane i reads lane i-n; row_shl:n = lane i+n)
template<int CTRL>
__device__ __forceinline__ float dppf(float oldv, float x) {
    return __int_as_float(__builtin_amdgcn_update_dpp(
        __float_as_int(oldv), __float_as_int(x), CTRL, 0xF, 0xF, false));
}

__device__ __forceinline__ float row16_sum(float x) {
    x += dppf<0xB1>(0.0f, x);    // quad_perm(1,0,3,2)
    x += dppf<0x4E>(0.0f, x);    // quad_perm(2,3,0,1)
    x += dppf<0x141>(0.0f, x);   // row_half_mirror
    x += dppf<0x140>(0.0f, x);   // row_mirror
    return x;
}
__device__ __forceinline__ float row16_prod(float x) {
    x *= dppf<0xB1>(1.0f, x);
    x *= dppf<0x4E>(1.0f, x);
    x *= dppf<0x141>(1.0f, x);
    x *= dppf<0x140>(1.0f, x);
    return x;
}

// One wave = 4 rays (16 lanes/ray), strided ownership: lane m owns samples
// {16*jj + m}, jj=0..7. ALL loads issued up front (16-deep MLP). Cross-lane
// ops are pure DPP. Fused finale with agent-scope (no-wbl2) publication.
__global__ __launch_bounds__(256) void integrate_kernel(
    const float* __restrict__ raw,     // [N][128][4]
    const float* __restrict__ zvals,   // [N][128]
    const float* __restrict__ rays_d,  // [N][3]
    float* __restrict__ chs_map,       // [N][3]
    float* __restrict__ depth_map,     // [N]
    float* __restrict__ block_partials,
    int* __restrict__ counter,
    float* __restrict__ sparsity_out)
{
    const int lane = threadIdx.x & 63;
    const int warp = threadIdx.x >> 6;
    const int g    = lane >> 4;   // ray within wave
    const int m    = lane & 15;   // lane within ray group

    const int gw  = blockIdx.x * 4 + warp;   // 0..16383
    const int ray = gw * 4 + g;              // 0..65535

    // ---- issue ALL global loads up front (max memory-level parallelism) ----
    const float* rd = rays_d + (size_t)ray * 3;
    const float d0 = rd[0], d1 = rd[1], d2 = rd[2];

    const float* zr = zvals + (size_t)ray * 128;
    float z[8];
    #pragma unroll
    for (int jj = 0; jj < 8; ++jj) z[jj] = zr[16*jj + m];

    const float4* rq = (const float4*)raw + (size_t)ray * 128;
    float4 q[8];
    #pragma unroll
    for (int jj = 0; jj < 8; ++jj) q[jj] = rq[16*jj + m];

    const float norm = sqrtf(d0*d0 + d1*d1 + d2*d2);

    float c0=0.f, c1=0.f, c2=0.f, wsum=0.f, dnum=0.f, aa=0.f;
    float carry = 1.0f;

    #pragma unroll
    for (int jj = 0; jj < 8; ++jj) {
        const float zc = z[jj];
        // z[s+1]: lane 15 takes next chunk's lane-0 z via row_shr:15, then
        // everyone else shifts via row_shl:1 (lane 15 keeps the fixed value)
        const float znfix = dppf<0x11F>(zc, z[(jj < 7) ? jj+1 : jj]);
        const float zn    = dppf<0x101>(znfix, zc);
        const bool  last  = (jj == 7) && (m == 15);   // s == 127
        const float dn    = last ? (1e10f * norm) : ((zn - zc) * norm);

        const float sig   = fmaxf(q[jj].w, 0.0f);
        const float e     = __expf(-sig * dn);
        const float alpha = 1.0f - e;
        const float t     = e + 1e-10f;

        // inclusive product scan over the 16-lane chunk
        float sc = t;
        sc *= dppf<0x111>(1.0f, sc);   // row_shr:1
        sc *= dppf<0x112>(1.0f, sc);   // row_shr:2
        sc *= dppf<0x114>(1.0f, sc);   // row_shr:4
        sc *= dppf<0x118>(1.0f, sc);   // row_shr:8
        const float E = dppf<0x111>(1.0f, sc);   // exclusive (lane0 = 1)
        const float T = row16_prod(t);           // chunk total (all lanes)

        const float trans = carry * E;
        const float w     = alpha * trans;
        c0   += w * q[jj].x;
        c1   += w * q[jj].y;
        c2   += w * q[jj].z;
        wsum += w;
        dnum += w * (6.0f - zc) * 0.25f;
        aa   += w * __logf(fmaxf(w, 1e-30f));    // w==0 -> 0
        carry *= T;
    }

    // 6-var allreduce within the 16-lane group (pure DPP)
    c0   = row16_sum(c0);
    c1   = row16_sum(c1);
    c2   = row16_sum(c2);
    wsum = row16_sum(wsum);
    dnum = row16_sum(dnum);
    aa   = row16_sum(aa);

    float ent = 0.0f;
    if (m == 0) {
        chs_map[(size_t)ray * 3 + 0] = c0;
        chs_map[(size_t)ray * 3 + 1] = c1;
        chs_map[(size_t)ray * 3 + 2] = c2;
        depth_map[ray] = dnum / (wsum + 1e-5f);

        // sum p*log p = (A - W*log(psum) + L*(log L - log psum)) / psum
        const float L = 1.0f - wsum + 1e-6f;
        const float psum = wsum + L;
        const float logpsum = __logf(psum);
        const float entL = (L > 0.0f) ? L * (__logf(L) - logpsum) : 0.0f;
        ent = -(aa - wsum * logpsum + entL) / psum;
    }
    // partials live on lanes 0,16,32,48 -> lane 0
    ent += __shfl_xor(ent, 16);
    ent += __shfl_xor(ent, 32);

    __shared__ float sred[4];
    __shared__ int slast;
    if (lane == 0) sred[warp] = ent;
    __syncthreads();
    if (threadIdx.x == 0) {
        const float part = sred[0] + sred[1] + sred[2] + sred[3];
        // agent-scope write-through store (NO buffer_wbl2, unlike __threadfence)
        __hip_atomic_store(&block_partials[blockIdx.x], part,
                           __ATOMIC_RELAXED, __HIP_MEMORY_SCOPE_AGENT);
        // ensure the coherent-point store retired before taking a ticket
        asm volatile("s_waitcnt vmcnt(0)" ::: "memory");
        const int t = __hip_atomic_fetch_add(counter, 1, __ATOMIC_RELAXED,
                                             __HIP_MEMORY_SCOPE_AGENT);
        slast = (t == NBLK - 1) ? 1 : 0;
    }
    __syncthreads();   // slast uniform across block

    if (slast) {
        // last-finishing block: all partials are at the coherent point.
        // Fixed per-thread assignment -> bit-deterministic sum.
        float s2 = 0.0f;
        #pragma unroll
        for (int i = 0; i < NBLK / 256; ++i)
            s2 += __hip_atomic_load(&block_partials[threadIdx.x + i * 256],
                                    __ATOMIC_RELAXED, __HIP_MEMORY_SCOPE_AGENT);
        #pragma unroll
        for (int d = 1; d < 64; d <<= 1) s2 += __shfl_xor(s2, d);
        __shared__ float sr2[4];
        if (lane == 0) sr2[warp] = s2;
        __syncthreads();
        if (threadIdx.x == 0)
            *sparsity_out = sr2[0] + sr2[1] + sr2[2] + sr2[3];
    }
}

extern "C" void kernel_launch(void* const* d_in, const int* in_sizes, int n_in,
                              void* d_out, int out_size, void* d_ws, size_t ws_size,
                              hipStream_t stream) {
    const float* raw    = (const float*)d_in[0];
    const float* zvals  = (const float*)d_in[1];
    const float* rays_d = (const float*)d_in[2];

    float* out = (float*)d_out;
    float* chs_map   = out;                       // 65536*3
    float* depth_map = out + (size_t)N_RAYS * 3;  // 65536
    float* sparsity  = out + (size_t)N_RAYS * 4;  // 1

    float* partials = (float*)d_ws;                         // NBLK floats
    int*   counter  = (int*)((char*)d_ws + NBLK * sizeof(float));

    // re-zero the ticket each launch (4B; d_ws is not re-poisoned between replays)
    hipMemsetAsync(counter, 0, sizeof(int), stream);

    integrate_kernel<<<NBLK, 256, 0, stream>>>(raw, zvals, rays_d,
                                               chs_map, depth_map,
                                               partials, counter, sparsity);
}